// Round 23
// baseline (81.919 us; speedup 1.0000x reference)
//
#include <hip/hip_runtime.h>

// VQ via MFMA (bf16 hi/lo compensated) + exact-recheck for near-ties. R23.
// x [64,64,32,32] fp32, E [64,1024] fp32. rows n = b*1024+hw, N=65536.
// d_out: [0,4194304) quantized; [4194304] dict_loss; [4194305] commit_loss;
//   [4194306,+65536) indices as float.
// R23 = R16's best-measured matmul geometry (8-kt phases, 2x32KB = 64KB LDS,
// esq from GLOBAL consumed at chain end) + R21/R22's counted-vmcnt barrier
// protocol (VMWAIT(8), never 0 mid-loop) + T5 s_setprio(1) around each MFMA
// cluster (guide: +21-39% on counted-vmcnt phase structures, m218b/m224) +
// fused cleanup/epilogue (xlds/klds/redlds alias dead blds).

#define DDIM 64
#define KNUM 1024
#define HWN  1024
#define EPSS 0.01f   // score-space flag gap; 3-term bf16 err <= ~3e-3

typedef __attribute__((ext_vector_type(8))) short short8v;
typedef __attribute__((ext_vector_type(4))) float f32x4;

#define VMWAIT(N) do { asm volatile("s_waitcnt vmcnt(" #N ")" ::: "memory"); \
                       __builtin_amdgcn_sched_barrier(0); } while (0)

__device__ __forceinline__ unsigned short bf16_rn(float v) {
    unsigned u = __float_as_uint(v);
    return (unsigned short)((u + 0x7FFFu + ((u >> 16) & 1u)) >> 16);
}
__device__ __forceinline__ float bf16f(unsigned short h) {
    return __uint_as_float(((unsigned)h) << 16);
}

// ---- E: esqm = -|e|^2/2 + bf16 hi/lo split, transposed to [k][d] ----
__global__ __launch_bounds__(256) void vq_convert_e(const float* __restrict__ E,
                                                    float* __restrict__ esqm,
                                                    unsigned short* __restrict__ eh,
                                                    unsigned short* __restrict__ el) {
    int k = blockIdx.x * 256 + threadIdx.x;   // grid 4
    float s = 0.f;
    #pragma unroll 8
    for (int d = 0; d < DDIM; ++d) {
        float v = E[d * KNUM + k];
        s = fmaf(v, v, s);
        unsigned short h = bf16_rn(v);
        float lo = v - bf16f(h);              // exact split
        eh[k * DDIM + d] = h;
        el[k * DDIM + d] = bf16_rn(lo);
    }
    esqm[k] = -0.5f * s;
}

// ---- fused: MFMA scores + top2 argmax + cleanup + quantized + loss ----
__global__ __launch_bounds__(256, 2) void vq_mfma_fused(const float* __restrict__ x,
                                                        const float* __restrict__ E,
                                                        const unsigned short* __restrict__ eh,
                                                        const unsigned short* __restrict__ el,
                                                        const float* __restrict__ esqm,
                                                        float* __restrict__ oidx,
                                                        float* __restrict__ out_q,
                                                        float* __restrict__ partial) {
    // blds[buf]: 8 kt-tiles x (32 rows x 128 B swizzled) = 32 KB per buffer.
    // Total 64 KB static; epilogue xlds/klds/redlds alias this after the loop.
    __shared__ unsigned short blds[2][16384];

    const int t = threadIdx.x;
    const int wv = t >> 6, l = t & 63;
    const int m = l & 15, g = l >> 4;
    const int tile = blockIdx.x * 4 + wv;     // grid 1024: 4096 tiles, 1/wave
    const int n0 = blockIdx.x * 64;
    const int b  = n0 >> 10, hw0 = n0 & 1023;

    // ---- B staging: 256 threads stage one 4KB kt-tile; linear dest ----
    const int sr   = t >> 3;                  // row 0..31 in tile
    const int sc   = (t & 7) * 16;            // linear byte col
    const int scsw = sc ^ ((sr & 7) << 4);    // inverse-swizzled source col
    const unsigned short* srcrow0 =
        (sr < 16) ? (eh + (size_t)sr * DDIM + (scsw >> 1))
                  : (el + (size_t)(sr - 16) * DDIM + (scsw >> 1));
    // stage phase P (8 kt-tiles, 8 loads/thread) into BUF
    #define STAGEPH(BUF, P)                                                                  \
        _Pragma("unroll")                                                                    \
        for (int q = 0; q < 8; ++q)                                                          \
            __builtin_amdgcn_global_load_lds(                                                \
                (const __attribute__((address_space(1))) void*)(srcrow0 + (size_t)((P) * 8 + q) * 16 * DDIM), \
                (__attribute__((address_space(3))) void*)&blds[BUF][q * 2048 + t * 8],       \
                16, 0, 0);

    // ---- A fragments: load x fp32 (coalesced), split hi/lo in-reg ----
    short8v axh[2], axl[2];
    {
        const int tn0 = tile * 16;
        const int tb = tn0 >> 10, thw = tn0 & 1023;
        const float* xg = x + (size_t)tb * (DDIM * HWN) + thw + m;
        #pragma unroll
        for (int s = 0; s < 2; ++s) {
            #pragma unroll
            for (int i = 0; i < 8; ++i) {
                float v = xg[(s * 32 + g * 8 + i) * HWN];
                unsigned short h = bf16_rn(v);
                axh[s][i] = (short)h;
                axl[s][i] = (short)bf16_rn(v - bf16f(h));
            }
        }
    }

    // swizzled ds_read offsets (shorts) within a kt-tile
    const int off_h0 = (m * 128 + (((g * 16)     ) ^ ((m & 7) << 4))) >> 1;
    const int off_h1 = (m * 128 + (((64 + g * 16)) ^ ((m & 7) << 4))) >> 1;
    const int off_l0 = off_h0 + 1024;
    const int off_l1 = off_h1 + 1024;

    float max1[4], max2[4]; int bk[4];
    #pragma unroll
    for (int j = 0; j < 4; ++j) { max1[j] = -3.4e38f; max2[j] = -3.4e38f; bk[j] = 0; }

    const f32x4 zf = {0.f, 0.f, 0.f, 0.f};

    STAGEPH(0, 0);

    for (int p = 0; p < 8; ++p) {
        const int cur = p & 1;
        __builtin_amdgcn_s_barrier();         // all waves done with buf cur^1
        if (p < 7) { STAGEPH(cur ^ 1, p + 1); VMWAIT(8); }  // drain all older
        else       { VMWAIT(0); }
        __builtin_amdgcn_s_barrier();         // every wave drained its stage

        __builtin_amdgcn_s_setprio(1);        // T5: favor compute waves
        #pragma unroll
        for (int ktl = 0; ktl < 8; ++ktl) {
            const int kt = p * 8 + ktl;
            const unsigned short* bb = &blds[cur][ktl * 2048];
            const short8v bh0 = *reinterpret_cast<const short8v*>(bb + off_h0);
            const short8v bh1 = *reinterpret_cast<const short8v*>(bb + off_h1);
            const short8v bl0 = *reinterpret_cast<const short8v*>(bb + off_l0);
            const short8v bl1 = *reinterpret_cast<const short8v*>(bb + off_l1);
            const float ci = esqm[kt * 16 + m];   // global L2, consumed at end
            const int kcur = kt * 16 + m;

            // three independent 2-deep chains
            f32x4 a0, a1, a2;
            a0 = __builtin_amdgcn_mfma_f32_16x16x32_bf16(axh[0], bh0, zf, 0, 0, 0);
            a1 = __builtin_amdgcn_mfma_f32_16x16x32_bf16(axh[0], bl0, zf, 0, 0, 0);
            a2 = __builtin_amdgcn_mfma_f32_16x16x32_bf16(axl[0], bh0, zf, 0, 0, 0);
            a0 = __builtin_amdgcn_mfma_f32_16x16x32_bf16(axh[1], bh1, a0, 0, 0, 0);
            a1 = __builtin_amdgcn_mfma_f32_16x16x32_bf16(axh[1], bl1, a1, 0, 0, 0);
            a2 = __builtin_amdgcn_mfma_f32_16x16x32_bf16(axl[1], bh1, a2, 0, 0, 0);

            #pragma unroll
            for (int j = 0; j < 4; ++j) {
                float s = (a0[j] + a1[j]) + (a2[j] + ci);   // score = Sxe - esq/2
                max2[j] = fmaxf(fminf(s, max1[j]), max2[j]); // med3-style top-2
                bool gt = s > max1[j];
                bk[j]   = gt ? kcur : bk[j];
                max1[j] = fmaxf(max1[j], s);
            }
        }
        __builtin_amdgcn_s_setprio(0);
    }
    #undef STAGEPH

    __syncthreads();   // loop done everywhere (full drain, once)

    // ---- epilogue scratch aliases dead blds: xlds 16KB | klds | redlds ----
    float* xlds   = reinterpret_cast<float*>(&blds[0][0]);          // [64][64]
    int*   klds   = reinterpret_cast<int*>(&blds[0][0]) + 4096;     // 64 ints
    float* redlds = reinterpret_cast<float*>(&blds[0][0]) + 4160;   // 4 floats
    {
        const float* xbase = x + (size_t)b * (DDIM * HWN) + hw0;
        #pragma unroll
        for (int it = 0; it < 4; ++it) {
            int dbase = it * 16 + wv * 4;
            int dsub  = l >> 4;
            int off   = (l & 15) * 4;
            const float* gp = xbase + (dbase + dsub) * HWN + off;
            __builtin_amdgcn_global_load_lds(
                (const __attribute__((address_space(1))) void*)gp,
                (__attribute__((address_space(3))) void*)&xlds[dbase * 64 + l * 4],
                16, 0, 0);
        }
    }

    // ---- top-2 merge (max semantics) across the 16 k-class lanes ----
    #pragma unroll
    for (int j = 0; j < 4; ++j) {
        float m1 = max1[j], m2 = max2[j]; int k1 = bk[j];
        #pragma unroll
        for (int off = 8; off >= 1; off >>= 1) {
            float om1 = __shfl_xor(m1, off, 16);
            float om2 = __shfl_xor(m2, off, 16);
            int   ok1 = __shfl_xor(k1, off, 16);
            if (om1 > m1 || (om1 == m1 && ok1 < k1)) {
                m2 = fmaxf(m1, om2); m1 = om1; k1 = ok1;
            } else {
                m2 = fmaxf(m2, om1);   // a tied/lower om1 IS a 2nd-best candidate
            }
        }
        if (m == j) {
            int r = wv * 16 + g * 4 + j;
            klds[r] = (m1 - m2 < EPSS) ? -(k1 + 1) : k1;   // negative = flagged
        }
    }
    __syncthreads();   // xlds staged (barrier drains vmcnt) + klds visible

    // ---- cleanup: exact fp32 recheck (score space) for flagged rows ----
    for (int r = wv; r < 64; r += 4) {
        if (klds[r] >= 0) continue;
        float acc[16];
        #pragma unroll
        for (int kk = 0; kk < 16; ++kk) acc[kk] = 0.f;
        for (int d = 0; d < DDIM; ++d) {
            float xd = xlds[d * 64 + r];                   // broadcast
            #pragma unroll
            for (int kk = 0; kk < 16; ++kk)
                acc[kk] = fmaf(xd, E[d * KNUM + kk * 64 + l], acc[kk]);
        }
        float bm = -3.4e38f; int bkk = KNUM;
        #pragma unroll
        for (int kk = 0; kk < 16; ++kk) {
            int k = kk * 64 + l;
            float sc = acc[kk] + esqm[k];                  // score space
            if (sc > bm) { bm = sc; bkk = k; }             // kk ascending -> first-max
        }
        #pragma unroll
        for (int off = 32; off >= 1; off >>= 1) {
            float ob = __shfl_xor(bm, off);
            int   ok = __shfl_xor(bkk, off);
            if (ob > bm || (ob == bm && ok < bkk)) { bm = ob; bkk = ok; }
        }
        if (l == 0) klds[r] = bkk;
    }
    __syncthreads();

    // ---- gather quantized, write coalesced, loss partial, indices ----
    float lsum = 0.f;
    float* outbase = out_q + (size_t)b * (DDIM * HWN) + hw0;
    #pragma unroll 4
    for (int it = 0; it < 16; ++it) {
        int d = it * 4 + (t >> 6);
        int r = t & 63;
        int k = klds[r];
        float q  = E[d * KNUM + k];
        float xv = xlds[d * 64 + r];
        float diff = xv - q;
        lsum = fmaf(diff, diff, lsum);
        outbase[d * HWN + r] = q;
    }
    if (t < 64) oidx[n0 + t] = (float)klds[t];

    #pragma unroll
    for (int off = 32; off >= 1; off >>= 1)
        lsum += __shfl_xor(lsum, off);
    if ((t & 63) == 0) redlds[t >> 6] = lsum;
    __syncthreads();
    if (t == 0)
        partial[blockIdx.x] = (redlds[0] + redlds[1]) + (redlds[2] + redlds[3]);
}

__global__ __launch_bounds__(256) void vq_loss_kernel(const float* __restrict__ partial,
                                                      float* __restrict__ out_loss) {
    __shared__ float red[4];
    int t = threadIdx.x;
    float s = 0.f;
    #pragma unroll
    for (int it = 0; it < 4; ++it) s += partial[it * 256 + t];
    #pragma unroll
    for (int off = 32; off >= 1; off >>= 1) s += __shfl_xor(s, off);
    if ((t & 63) == 0) red[t >> 6] = s;
    __syncthreads();
    if (t == 0) {
        float loss = ((red[0] + red[1]) + (red[2] + red[3])) / 4194304.f;
        out_loss[0] = loss;
        out_loss[1] = loss;
    }
}

extern "C" void kernel_launch(void* const* d_in, const int* in_sizes, int n_in,
                              void* d_out, int out_size, void* d_ws, size_t ws_size,
                              hipStream_t stream) {
    const float* x = (const float*)d_in[0];
    const float* E = (const float*)d_in[1];
    float* out      = (float*)d_out;
    float* out_q    = out;
    float* out_loss = out + 4194304;
    float* oidx     = out + 4194306;

    float* esqm    = (float*)d_ws;                           // 1024 f32 (-esq/2)
    float* partial = esqm + 1024;                            // 1024 f32
    unsigned short* eh = (unsigned short*)(partial + 1024);  // 65536 us
    unsigned short* el = eh + KNUM * DDIM;                   // 65536 us

    vq_convert_e<<<4, 256, 0, stream>>>(E, esqm, eh, el);
    vq_mfma_fused<<<1024, 256, 0, stream>>>(x, E, eh, el, esqm, oidx, out_q, partial);
    vq_loss_kernel<<<1, 256, 0, stream>>>(partial, out_loss);
}

// Round 24
// 64.318 us; speedup vs baseline: 1.2737x; 1.2737x over previous
//
#include <hip/hip_runtime.h>

// VQ via MFMA (bf16 hi/lo compensated) + exact-recheck for near-ties. FINAL
// (= R18, the best-measured variant: 63.8 us total, fused 60.7 us).
// x [64,64,32,32] fp32, E [64,1024] fp32. rows n = b*1024+hw, N=65536.
// d_out: [0,4194304) quantized; [4194304] dict_loss; [4194305] commit_loss;
//   [4194306,+65536) indices as float.
//
// Structure: convert_e (esq + exact bf16 hi/lo split of E, [k][d]) ->
// fused kernel: per-block 64 rows; 4-kt double-buffered B tiles in LDS
// (global_load_lds, XOR-swizzled layout), 6-MFMA compensated chain with
// C-init = -esq/2 (score space: argmin dist == argmax score), med3-style
// per-lane top-2, 16-lane shuffle merge, near-ties (gap < EPSS) flagged and
// exactly recomputed in fp32, then gather/quantized/loss epilogue in-kernel.
//
// Session notes (counter-driven): MFMA-pipe busy ~= its 10.3 us floor;
// variants T=1/2, 4/8-kt phases, counted-vmcnt, chain-split, setprio all
// land 60+-4 us (latency-bound, no pipe >35%). This config won.

#define DDIM 64
#define KNUM 1024
#define HWN  1024
#define EPSS 0.01f   // score-space flag gap; 3-term bf16 err <= ~3e-3

typedef __attribute__((ext_vector_type(8))) short short8v;
typedef __attribute__((ext_vector_type(4))) float f32x4;

__device__ __forceinline__ unsigned short bf16_rn(float v) {
    unsigned u = __float_as_uint(v);
    return (unsigned short)((u + 0x7FFFu + ((u >> 16) & 1u)) >> 16);
}
__device__ __forceinline__ float bf16f(unsigned short h) {
    return __uint_as_float(((unsigned)h) << 16);
}

// ---- E: esq + bf16 hi/lo split, transposed to [k][d] ----
__global__ __launch_bounds__(256) void vq_convert_e(const float* __restrict__ E,
                                                    float* __restrict__ esq,
                                                    unsigned short* __restrict__ eh,
                                                    unsigned short* __restrict__ el) {
    int k = blockIdx.x * 256 + threadIdx.x;   // grid 4
    float s = 0.f;
    #pragma unroll 8
    for (int d = 0; d < DDIM; ++d) {
        float v = E[d * KNUM + k];
        s = fmaf(v, v, s);
        unsigned short h = bf16_rn(v);
        float lo = v - bf16f(h);              // exact split
        eh[k * DDIM + d] = h;
        el[k * DDIM + d] = bf16_rn(lo);
    }
    esq[k] = s;
}

// ---- fused: MFMA scores + top2 argmax + cleanup + quantized + loss ----
__global__ __launch_bounds__(256, 4) void vq_mfma_fused(const float* __restrict__ x,
                                                        const float* __restrict__ E,
                                                        const unsigned short* __restrict__ eh,
                                                        const unsigned short* __restrict__ el,
                                                        const float* __restrict__ esq,
                                                        float* __restrict__ oidx,
                                                        float* __restrict__ out_q,
                                                        float* __restrict__ partial) {
    // blds[buf]: 4 kt-tiles x (32 rows x 128 B swizzled) = 16 KB per buffer.
    __shared__ unsigned short blds[2][8192];
    __shared__ float esqlds[KNUM];            // 4 KB, staged once
    __shared__ int   klds[64];
    __shared__ float redlds[4];

    const int t = threadIdx.x;
    const int wv = t >> 6, l = t & 63;
    const int m = l & 15, g = l >> 4;
    const int tile = blockIdx.x * 4 + wv;     // grid 1024: 4096 tiles, 1/wave
    const int n0 = blockIdx.x * 64;
    const int b  = n0 >> 10, hw0 = n0 & 1023;

    // ---- stage esq once (4 KB = 256 x 16 B); drained by first barrier ----
    __builtin_amdgcn_global_load_lds(
        (const __attribute__((address_space(1))) void*)(esq + t * 4),
        (__attribute__((address_space(3))) void*)&esqlds[t * 4], 16, 0, 0);

    // ---- staging geometry: 256 threads stage one 4KB kt-tile ----
    const int sr   = t >> 3;                  // row 0..31 in tile
    const int sc   = (t & 7) * 16;            // linear byte col
    const int scsw = sc ^ ((sr & 7) << 4);    // inverse-swizzled source col
    const unsigned short* srcrow0 =
        (sr < 16) ? (eh + (size_t)sr * DDIM + (scsw >> 1))
                  : (el + (size_t)(sr - 16) * DDIM + (scsw >> 1));
    #define STAGEPH(BUF, P)                                                                  \
        _Pragma("unroll")                                                                    \
        for (int q = 0; q < 4; ++q)                                                          \
            __builtin_amdgcn_global_load_lds(                                                \
                (const __attribute__((address_space(1))) void*)(srcrow0 + (size_t)((P) * 4 + q) * 16 * DDIM), \
                (__attribute__((address_space(3))) void*)&blds[BUF][q * 2048 + t * 8],       \
                16, 0, 0);

    // ---- A fragments: load x fp32 (coalesced), split hi/lo in-reg ----
    short8v axh[2], axl[2];
    {
        const int tn0 = tile * 16;
        const int tb = tn0 >> 10, thw = tn0 & 1023;
        const float* xg = x + (size_t)tb * (DDIM * HWN) + thw + m;
        #pragma unroll
        for (int s = 0; s < 2; ++s) {
            #pragma unroll
            for (int i = 0; i < 8; ++i) {
                float v = xg[(s * 32 + g * 8 + i) * HWN];
                unsigned short h = bf16_rn(v);
                axh[s][i] = (short)h;
                axl[s][i] = (short)bf16_rn(v - bf16f(h));
            }
        }
    }

    // swizzled ds_read offsets (shorts) within a kt-tile
    const int off_h0 = (m * 128 + (((g * 16)     ) ^ ((m & 7) << 4))) >> 1;
    const int off_h1 = (m * 128 + (((64 + g * 16)) ^ ((m & 7) << 4))) >> 1;
    const int off_l0 = off_h0 + 1024;
    const int off_l1 = off_h1 + 1024;

    float max1[4], max2[4]; int bk[4];
    #pragma unroll
    for (int j = 0; j < 4; ++j) { max1[j] = -3.4e38f; max2[j] = -3.4e38f; bk[j] = 0; }

    STAGEPH(0, 0);
    __syncthreads();

    for (int p = 0; p < 16; ++p) {
        const int cur = p & 1;
        if (p < 15) STAGEPH(cur ^ 1, p + 1);

        #pragma unroll
        for (int ktl = 0; ktl < 4; ++ktl) {
            const int kt = p * 4 + ktl;
            const unsigned short* bb = &blds[cur][ktl * 2048];
            const short8v bh0 = *reinterpret_cast<const short8v*>(bb + off_h0);
            const short8v bh1 = *reinterpret_cast<const short8v*>(bb + off_h1);
            const short8v bl0 = *reinterpret_cast<const short8v*>(bb + off_l0);
            const short8v bl1 = *reinterpret_cast<const short8v*>(bb + off_l1);
            const float ci = -0.5f * esqlds[kt * 16 + m];   // ds_read, lgkm domain
            const f32x4 cinit = {ci, ci, ci, ci};           // per-col splat (legal)

            f32x4 acc;
            acc = __builtin_amdgcn_mfma_f32_16x16x32_bf16(axh[0], bh0, cinit, 0, 0, 0);
            acc = __builtin_amdgcn_mfma_f32_16x16x32_bf16(axh[1], bh1, acc,  0, 0, 0);
            acc = __builtin_amdgcn_mfma_f32_16x16x32_bf16(axh[0], bl0, acc,  0, 0, 0);
            acc = __builtin_amdgcn_mfma_f32_16x16x32_bf16(axh[1], bl1, acc,  0, 0, 0);
            acc = __builtin_amdgcn_mfma_f32_16x16x32_bf16(axl[0], bh0, acc,  0, 0, 0);
            acc = __builtin_amdgcn_mfma_f32_16x16x32_bf16(axl[1], bh1, acc,  0, 0, 0);

            const int kcur = kt * 16 + m;
            #pragma unroll
            for (int j = 0; j < 4; ++j) {
                float s = acc[j];                       // score = Sxe - esq/2
                max2[j] = fmaxf(fminf(s, max1[j]), max2[j]);   // med3-style
                bool gt = s > max1[j];
                bk[j]   = gt ? kcur : bk[j];
                max1[j] = fmaxf(max1[j], s);
            }
        }
        __syncthreads();
    }
    #undef STAGEPH

    // ---- issue x fp32 staging into dead blds (overlaps with merge below) ----
    float* xlds = reinterpret_cast<float*>(&blds[0][0]);   // 16 KB [d][64 rows]
    {
        const float* xbase = x + (size_t)b * (DDIM * HWN) + hw0;
        #pragma unroll
        for (int it = 0; it < 4; ++it) {
            int dbase = it * 16 + wv * 4;
            int dsub  = l >> 4;
            int off   = (l & 15) * 4;
            const float* gp = xbase + (dbase + dsub) * HWN + off;
            __builtin_amdgcn_global_load_lds(
                (const __attribute__((address_space(1))) void*)gp,
                (__attribute__((address_space(3))) void*)&xlds[dbase * 64 + l * 4],
                16, 0, 0);
        }
    }

    // ---- top-2 merge (max semantics) across the 16 k-class lanes ----
    #pragma unroll
    for (int j = 0; j < 4; ++j) {
        float m1 = max1[j], m2 = max2[j]; int k1 = bk[j];
        #pragma unroll
        for (int off = 8; off >= 1; off >>= 1) {
            float om1 = __shfl_xor(m1, off, 16);
            float om2 = __shfl_xor(m2, off, 16);
            int   ok1 = __shfl_xor(k1, off, 16);
            if (om1 > m1 || (om1 == m1 && ok1 < k1)) {
                m2 = fmaxf(m1, om2); m1 = om1; k1 = ok1;
            } else {
                m2 = fmaxf(m2, (om1 == m1) ? om2 : om1);
            }
        }
        if (m == j) {
            int r = wv * 16 + g * 4 + j;
            klds[r] = (m1 - m2 < EPSS) ? -(k1 + 1) : k1;   // negative = flagged
        }
    }
    __syncthreads();   // xlds staged (vmcnt drained) + klds visible

    // ---- cleanup: exact fp32 recheck for flagged rows (rare) ----
    for (int r = wv; r < 64; r += 4) {
        if (klds[r] >= 0) continue;
        float acc[16];
        #pragma unroll
        for (int kk = 0; kk < 16; ++kk) acc[kk] = 0.f;
        for (int d = 0; d < DDIM; ++d) {
            float xd = xlds[d * 64 + r];                   // broadcast
            #pragma unroll
            for (int kk = 0; kk < 16; ++kk)
                acc[kk] = fmaf(xd, E[d * KNUM + kk * 64 + l], acc[kk]);
        }
        float bm = 3.4e38f; int bkk = KNUM;
        #pragma unroll
        for (int kk = 0; kk < 16; ++kk) {
            int k = kk * 64 + l;
            float dist = fmaf(-2.f, acc[kk], esqlds[k]);
            if (dist < bm) { bm = dist; bkk = k; }         // kk ascending -> first-min
        }
        #pragma unroll
        for (int off = 32; off >= 1; off >>= 1) {
            float ob = __shfl_xor(bm, off);
            int   ok = __shfl_xor(bkk, off);
            if (ob < bm || (ob == bm && ok < bkk)) { bm = ob; bkk = ok; }
        }
        if (l == 0) klds[r] = bkk;
    }
    __syncthreads();

    // ---- gather quantized, write coalesced, loss partial, indices ----
    float lsum = 0.f;
    float* outbase = out_q + (size_t)b * (DDIM * HWN) + hw0;
    #pragma unroll 4
    for (int it = 0; it < 16; ++it) {
        int d = it * 4 + (t >> 6);
        int r = t & 63;
        int k = klds[r];
        float q  = E[d * KNUM + k];
        float xv = xlds[d * 64 + r];
        float diff = xv - q;
        lsum = fmaf(diff, diff, lsum);
        outbase[d * HWN + r] = q;
    }
    if (t < 64) oidx[n0 + t] = (float)klds[t];

    #pragma unroll
    for (int off = 32; off >= 1; off >>= 1)
        lsum += __shfl_xor(lsum, off);
    if ((t & 63) == 0) redlds[t >> 6] = lsum;
    __syncthreads();
    if (t == 0)
        partial[blockIdx.x] = (redlds[0] + redlds[1]) + (redlds[2] + redlds[3]);
}

__global__ __launch_bounds__(256) void vq_loss_kernel(const float* __restrict__ partial,
                                                      float* __restrict__ out_loss) {
    __shared__ float red[4];
    int t = threadIdx.x;
    float s = 0.f;
    #pragma unroll
    for (int it = 0; it < 4; ++it) s += partial[it * 256 + t];
    #pragma unroll
    for (int off = 32; off >= 1; off >>= 1) s += __shfl_xor(s, off);
    if ((t & 63) == 0) red[t >> 6] = s;
    __syncthreads();
    if (t == 0) {
        float loss = ((red[0] + red[1]) + (red[2] + red[3])) / 4194304.f;
        out_loss[0] = loss;
        out_loss[1] = loss;
    }
}

extern "C" void kernel_launch(void* const* d_in, const int* in_sizes, int n_in,
                              void* d_out, int out_size, void* d_ws, size_t ws_size,
                              hipStream_t stream) {
    const float* x = (const float*)d_in[0];
    const float* E = (const float*)d_in[1];
    float* out      = (float*)d_out;
    float* out_q    = out;
    float* out_loss = out + 4194304;
    float* oidx     = out + 4194306;

    float* esq     = (float*)d_ws;                           // 1024 f32
    float* partial = esq + 1024;                             // 1024 f32
    unsigned short* eh = (unsigned short*)(partial + 1024);  // 65536 us
    unsigned short* el = eh + KNUM * DDIM;                   // 65536 us

    vq_convert_e<<<4, 256, 0, stream>>>(E, esq, eh, el);
    vq_mfma_fused<<<1024, 256, 0, stream>>>(x, E, eh, el, esq, oidx, out_q, partial);
    vq_loss_kernel<<<1, 256, 0, stream>>>(partial, out_loss);
}